// Round 1
// baseline (5769.659 us; speedup 1.0000x reference)
//
#include <hip/hip_runtime.h>
#include <math.h>

#define DDIM 768
#define KC 32        // k-chunk staged per iteration
#define MB 64        // db rows per chunk
#define QSTRIDE 36   // padded LDS stride (floats) for Q/DB tiles: 2-way banks only
#define SSTRIDE 67   // padded LDS stride (floats) for score tile: 2-way banks only
#define TOPB 8       // per-block top candidates kept per query
#define NQ 256       // queries == threads per block
#define NB_MAX 768   // scoring blocks (3 resident/CU * 256 CU)

// ---------------- query normalization ----------------
__global__ __launch_bounds__(256) void normalize_q(const float* __restrict__ q,
                                                   float* __restrict__ qn) {
    __shared__ float part[4];
    __shared__ float rqs;
    const int b = blockIdx.x, tid = threadIdx.x;
    float s = 0.f;
    for (int i = tid; i < DDIM; i += 256) {
        float v = q[(size_t)b * DDIM + i];
        s = fmaf(v, v, s);
    }
    for (int off = 32; off > 0; off >>= 1) s += __shfl_down(s, off, 64);
    if ((tid & 63) == 0) part[tid >> 6] = s;
    __syncthreads();
    if (tid == 0) {
        float t = part[0] + part[1] + part[2] + part[3];
        rqs = 1.f / fmaxf(sqrtf(t), 1e-12f);
    }
    __syncthreads();
    float rq = rqs;
    for (int i = tid; i < DDIM; i += 256)
        qn[(size_t)b * DDIM + i] = q[(size_t)b * DDIM + i] * rq;
}

// ---------------- scoring + per-block top-8 ----------------
// block: 256 thr = 16(ty: query sub-row) x 16(tx: db group of 4 rows)
// thread t owns query t's running top-8 across all its chunks.
__global__ __launch_bounds__(256) void score_topb(const float* __restrict__ qn,
                                                  const float* __restrict__ db,
                                                  float* __restrict__ cand_s,
                                                  int* __restrict__ cand_i,
                                                  int M, int nchunks, int nblocks) {
    __shared__ __align__(16) float smem[NQ * QSTRIDE + MB * QSTRIDE + MB];
    float* Qs = smem;                        // [256][36]
    float* DBs = smem + NQ * QSTRIDE;        // [64][36]
    float* rnorm = smem + NQ * QSTRIDE + MB * QSTRIDE;  // [64]
    float* Ss = smem;                        // [128][67] overlays Q tile (phase use)

    const int tid = threadIdx.x;
    const int ty = tid & 15;
    const int tx = tid >> 4;
    const int txr = tx * 4;

    float t8s[TOPB];
    int t8i[TOPB];
#pragma unroll
    for (int p = 0; p < TOPB; ++p) { t8s[p] = -INFINITY; t8i[p] = 0; }

    for (int chunk = blockIdx.x; chunk < nchunks; chunk += nblocks) {
        const int base = chunk * MB;
        float acc[16][4];
#pragma unroll
        for (int qi = 0; qi < 16; ++qi)
#pragma unroll
            for (int j = 0; j < 4; ++j) acc[qi][j] = 0.f;
        float norm2 = 0.f;

        for (int kc = 0; kc < DDIM; kc += KC) {
            __syncthreads();  // previous phase (compute/selection) done before overwrite
            // stage Q tile: 256 rows x 8 float4
#pragma unroll
            for (int it = 0; it < 8; ++it) {
                int i = tid + it * 256;
                int row = i >> 3, c4 = i & 7;
                float4 v = *(const float4*)(qn + (size_t)row * DDIM + kc + c4 * 4);
                *(float4*)&Qs[row * QSTRIDE + c4 * 4] = v;
            }
            // stage DB tile: 64 rows x 8 float4
#pragma unroll
            for (int it = 0; it < 2; ++it) {
                int i = tid + it * 256;
                int row = i >> 3, c4 = i & 7;
                int rg = base + row;
                float4 v = make_float4(0.f, 0.f, 0.f, 0.f);
                if (rg < M) v = *(const float4*)(db + (size_t)rg * DDIM + kc + c4 * 4);
                *(float4*)&DBs[row * QSTRIDE + c4 * 4] = v;
            }
            __syncthreads();
            // inline db row norms (one thread per row, accumulated across kc)
            if (tid < MB) {
#pragma unroll
                for (int c4 = 0; c4 < 8; ++c4) {
                    float4 v = *(float4*)&DBs[tid * QSTRIDE + c4 * 4];
                    norm2 = fmaf(v.x, v.x, fmaf(v.y, v.y, fmaf(v.z, v.z, fmaf(v.w, v.w, norm2))));
                }
            }
            // main FMA loop: 8 k4-iters x (16 q x 4 db x 4 k) = 2048 fma / thread / kc
            for (int k4 = 0; k4 < 8; ++k4) {
                float4 dd[4];
#pragma unroll
                for (int j = 0; j < 4; ++j)
                    dd[j] = *(float4*)&DBs[(txr + j) * QSTRIDE + k4 * 4];
#pragma unroll
                for (int qi = 0; qi < 16; ++qi) {
                    float4 qv = *(float4*)&Qs[(qi * 16 + ty) * QSTRIDE + k4 * 4];
#pragma unroll
                    for (int j = 0; j < 4; ++j) {
                        acc[qi][j] = fmaf(qv.w, dd[j].w,
                                      fmaf(qv.z, dd[j].z,
                                       fmaf(qv.y, dd[j].y,
                                        fmaf(qv.x, dd[j].x, acc[qi][j]))));
                    }
                }
            }
        }
        if (tid < MB) rnorm[tid] = (norm2 > 0.f) ? (1.f / sqrtf(norm2)) : 0.f;
        __syncthreads();  // compute done; rnorm visible; safe to overlay Ss on Qs

        float rdl[4];
        bool vld[4];
#pragma unroll
        for (int j = 0; j < 4; ++j) {
            rdl[j] = rnorm[txr + j];
            vld[j] = (base + txr + j) < M;
        }

        // two 128-query phases (keeps static LDS < 64 KB)
#pragma unroll
        for (int h = 0; h < 2; ++h) {
#pragma unroll
            for (int qi8 = 0; qi8 < 8; ++qi8) {
                const int qi = h * 8 + qi8;
                const int ql = qi8 * 16 + ty;  // local query row 0..127
#pragma unroll
                for (int j = 0; j < 4; ++j) {
                    Ss[ql * SSTRIDE + txr + j] =
                        vld[j] ? acc[qi][j] * rdl[j] : -INFINITY;
                }
            }
            __syncthreads();
            if ((tid >> 7) == h) {  // thread tid owns global query tid
                const float* srow = &Ss[(tid & 127) * SSTRIDE];
                for (int d0 = 0; d0 < MB; ++d0) {
                    float v = srow[d0];
                    if (v > t8s[TOPB - 1]) {
                        int vi = base + d0;
#pragma unroll
                        for (int p = 0; p < TOPB; ++p) {
                            bool take = v > t8s[p];
                            float ts = t8s[p]; int ti = t8i[p];
                            t8s[p] = take ? v : ts;  t8i[p] = take ? vi : ti;
                            v = take ? ts : v;       vi = take ? ti : vi;
                        }
                    }
                }
            }
            __syncthreads();
        }
    }
    // write candidates: [query][block][TOPB]
    size_t off = ((size_t)tid * nblocks + blockIdx.x) * TOPB;
#pragma unroll
    for (int p = 0; p < TOPB; ++p) {
        cand_s[off + p] = t8s[p];
        cand_i[off + p] = t8i[p];
    }
}

// ---------------- final exact top-K merge, one block per query ----------------
__global__ __launch_bounds__(256) void merge_topk(const float* __restrict__ cand_s,
                                                  const int* __restrict__ cand_i,
                                                  float* __restrict__ out,
                                                  int nblocks, int N, int K) {
    __shared__ float ms[NB_MAX * TOPB];
    __shared__ int   mi[NB_MAX * TOPB];
    __shared__ float rs[256];
    __shared__ int   ri[256];
    const int q = blockIdx.x, tid = threadIdx.x;
    const int ncand = nblocks * TOPB;
    for (int j = tid; j < ncand; j += 256) {
        ms[j] = cand_s[(size_t)q * ncand + j];
        mi[j] = cand_i[(size_t)q * ncand + j];
    }
    __syncthreads();
    for (int it = 0; it < K; ++it) {
        float bv = -INFINITY; int bp = -1;
        for (int j = tid; j < ncand; j += 256) {
            float v = ms[j];
            if (v > bv) { bv = v; bp = j; }
        }
        rs[tid] = bv; ri[tid] = bp;
        __syncthreads();
        for (int off = 128; off > 0; off >>= 1) {
            if (tid < off) {
                if (rs[tid + off] > rs[tid]) { rs[tid] = rs[tid + off]; ri[tid] = ri[tid + off]; }
            }
            __syncthreads();
        }
        if (tid == 0) {
            int pos = ri[0];
            out[(size_t)q * K + it] = rs[0];
            out[(size_t)N * K + (size_t)q * K + it] = (float)mi[pos];  // indices as f32
            ms[pos] = -INFINITY;
        }
        __syncthreads();
    }
}

extern "C" void kernel_launch(void* const* d_in, const int* in_sizes, int n_in,
                              void* d_out, int out_size, void* d_ws, size_t ws_size,
                              hipStream_t stream) {
    const float* q  = (const float*)d_in[0];
    const float* db = (const float*)d_in[1];
    const int N = in_sizes[0] / DDIM;        // 256
    const int M = in_sizes[1] / DDIM;        // 500000
    const int K = out_size / (2 * N);        // 16
    float* out = (float*)d_out;

    // workspace carve: [q_n fp32 N*D][cand_s][cand_i]
    char* p = (char*)d_ws;
    size_t qn_bytes = (((size_t)N * DDIM * 4) + 255) & ~(size_t)255;
    float* qn = (float*)p;
    p += qn_bytes;
    size_t rem = ws_size > qn_bytes ? ws_size - qn_bytes : 0;
    size_t per_block = (size_t)N * TOPB * 8;  // score f32 + idx i32 per block
    int nb = (int)(rem / per_block);
    if (nb > NB_MAX) nb = NB_MAX;
    if (nb < 1) nb = 1;
    const int nchunks = (M + MB - 1) / MB;
    if (nb > nchunks) nb = nchunks;
    float* cand_s = (float*)p;
    int*   cand_i = (int*)(p + (size_t)N * nb * TOPB * 4);

    hipLaunchKernelGGL(normalize_q, dim3(N), dim3(256), 0, stream, q, qn);
    hipLaunchKernelGGL(score_topb, dim3(nb), dim3(256), 0, stream,
                       qn, db, cand_s, cand_i, M, nchunks, nb);
    hipLaunchKernelGGL(merge_topk, dim3(N), dim3(256), 0, stream,
                       cand_s, cand_i, out, nb, N, K);
}